// Round 2
// baseline (620.885 us; speedup 1.0000x reference)
//
#include <hip/hip_runtime.h>

// Fused entmax(alpha=1.3) attention, fp32. B=16, N=2048, D=64.
// R6b: LDS-port debottleneck (R6 + compile fix: nontemporal float4 store must
// use a builtin ext_vector_type, not HIP_vector_type). R5 was LDS-read-bound:
// each wave read all of K (512 KB LDS) for only 2 q-rows -> 32 MB/CU LDS reads
// ~250 us port time. Now 4 q-rows/wave (16/block, grid 2048): K LDS reads
// halve to 16 MB/CU. Vectorized attn-row writeback (b128 LDS reads + dwordx4
// nt-stores). Sparse entmax machinery unchanged from R5.

#define NBATCH 16
#define NSEQ   2048
#define DHEAD  64
#define OUT_OFF (NBATCH * NSEQ * DHEAD)   // out first, attn second
#define INV_A    3.3333333f               // 1/(alpha-1)
#define INV_A_M1 2.3333333f
#define TK    128
#define PADK  68                          // K-tile LDS row stride (0 conflicts)
#define NTILE (NSEQ / TK)                 // 16
#define WREG  2176                        // per-wave float region: TK*PADK/4

typedef float vfloat4 __attribute__((ext_vector_type(4)));

__device__ __forceinline__ float fast_log2(float x) { return __builtin_amdgcn_logf(x); }
__device__ __forceinline__ float fast_exp2(float x) { return __builtin_amdgcn_exp2f(x); }

__global__ __launch_bounds__(256) void entmax_attn_kernel(
    const float* __restrict__ Q, const float* __restrict__ K,
    const float* __restrict__ V, float* __restrict__ Out)
{
    // phase 1: K tiles (128 x 68). phase 2/3: per-wave regions of 2176 floats:
    //   [0..1024)    prow   — one 1024-float attn segment buffer
    //   [1024..1152) cval   — compact values, then normalized p
    //   [1152..1280) cidx   — compact indices (stored as float, exact < 2048)
    __shared__ __align__(16) float smem[TK * PADK];
    __shared__ __align__(16) float q_lds[16][DHEAD];

    const int tid  = threadIdx.x;
    const int w    = tid >> 6;
    const int lane = tid & 63;

    // XCD pinning: batch b -> XCD b%8; K+V of 2 batches = 2 MB in 4 MB L2
    const int i   = blockIdx.x;       // 0..2047
    const int xcd = i & 7;
    const int j2  = i >> 3;           // 0..255
    const int b   = xcd + 8 * (j2 & 1);
    const int rb  = j2 >> 1;          // 0..127
    const int n0  = rb * 16;          // 16 q-rows per block

    const float* Kb = K + (size_t)b * NSEQ * DHEAD;
    const float* Vb = V + (size_t)b * NSEQ * DHEAD;

    // stage 16 q-rows: 256 threads = 16 rows x 16 float4
    {
        const int r = tid >> 4, g = tid & 15;
        ((float4*)q_lds[r])[g] =
            ((const float4*)(Q + ((size_t)b * NSEQ + (size_t)(n0 + r)) * DHEAD))[g];
    }

    // scores s[r][j]: q-row n0+4w+r vs key m = j*64+lane. compile-time indices only.
    float s[4][32];
    const float* q0p = q_lds[4 * w + 0];
    const float* q1p = q_lds[4 * w + 1];
    const float* q2p = q_lds[4 * w + 2];
    const float* q3p = q_lds[4 * w + 3];

    // ---------------- phase 1: QK^T, K tiled through LDS ----------------
    #pragma unroll
    for (int t = 0; t < NTILE; ++t) {
        __syncthreads();
        #pragma unroll 4
        for (int rep = 0; rep < 8; ++rep) {
            const int f = tid + rep * 256;
            const int m = f >> 4, g = f & 15;
            const float4 kv = ((const float4*)(Kb + (size_t)(t * TK + m) * DHEAD))[g];
            *(float4*)&smem[m * PADK + 4 * g] = kv;
        }
        __syncthreads();

        float a00 = 0.f, a01 = 0.f, a10 = 0.f, a11 = 0.f;
        float a20 = 0.f, a21 = 0.f, a30 = 0.f, a31 = 0.f;
        #pragma unroll 1
        for (int g = 0; g < 16; ++g) {
            const float4 k0 = *(const float4*)&smem[lane * PADK + 4 * g];
            const float4 k1 = *(const float4*)&smem[(64 + lane) * PADK + 4 * g];
            const float4 qa = *(const float4*)&q0p[4 * g];
            const float4 qb = *(const float4*)&q1p[4 * g];
            const float4 qc = *(const float4*)&q2p[4 * g];
            const float4 qd = *(const float4*)&q3p[4 * g];
            a00 += qa.x*k0.x + qa.y*k0.y + qa.z*k0.z + qa.w*k0.w;
            a01 += qa.x*k1.x + qa.y*k1.y + qa.z*k1.z + qa.w*k1.w;
            a10 += qb.x*k0.x + qb.y*k0.y + qb.z*k0.z + qb.w*k0.w;
            a11 += qb.x*k1.x + qb.y*k1.y + qb.z*k1.z + qb.w*k1.w;
            a20 += qc.x*k0.x + qc.y*k0.y + qc.z*k0.z + qc.w*k0.w;
            a21 += qc.x*k1.x + qc.y*k1.y + qc.z*k1.z + qc.w*k1.w;
            a30 += qd.x*k0.x + qd.y*k0.y + qd.z*k0.z + qd.w*k0.w;
            a31 += qd.x*k1.x + qd.y*k1.y + qd.z*k1.z + qd.w*k1.w;
        }
        s[0][2*t]   = a00 * 0.125f;
        s[0][2*t+1] = a01 * 0.125f;
        s[1][2*t]   = a10 * 0.125f;
        s[1][2*t+1] = a11 * 0.125f;
        s[2][2*t]   = a20 * 0.125f;
        s[2][2*t+1] = a21 * 0.125f;
        s[3][2*t]   = a30 * 0.125f;
        s[3][2*t+1] = a31 * 0.125f;
    }
    __syncthreads();   // all K reads done; smem becomes per-wave regions

    float* wreg = &smem[w * WREG];
    float* prow = wreg;
    float* cval = wreg + 1024;
    float* cidx = wreg + 1152;
    const unsigned long long lt_mask = (1ull << lane) - 1ull;
    const int na = n0 + 4 * w;

    #pragma unroll
    for (int r = 0; r < 4; ++r) {
        // row max (butterfly -> identical in all lanes)
        float mx = s[r][0];
        #pragma unroll
        for (int j = 1; j < 32; ++j) mx = fmaxf(mx, s[r][j]);
        #pragma unroll
        for (int off = 32; off >= 1; off >>= 1) mx = fmaxf(mx, __shfl_xor(mx, off, 64));
        #pragma unroll
        for (int j = 0; j < 32; ++j) s[r][j] -= mx;

        // ballot-compact elements > -1 (only these can be in the support)
        int base = 0;
        #pragma unroll
        for (int j = 0; j < 32; ++j) {
            const bool act = s[r][j] > -1.0f;
            const unsigned long long bm = __ballot(act);
            const int pos = base + __popcll(bm & lt_mask);
            if (act && pos < 128) {
                cval[pos] = s[r][j];
                cidx[pos] = (float)(j * 64 + lane);
            }
            base += __popcll(bm);
        }
        const int A = base;               // wave-uniform
        float outacc = 0.f;

        if (A <= 128) {
            // -------- sparse solver on <=2 compact elements per lane --------
            const float cv0 = cval[lane];
            const float cv1 = cval[64 + lane];
            const bool ok0 = (lane < A);
            const bool ok1 = (64 + lane < A);

            float lo = -1.0f, hi = -1e-6f;
            #pragma unroll 1
            for (int it = 0; it < 12; ++it) {
                const float tau = 0.5f * (lo + hi);
                const float t0 = cv0 - tau, t1 = cv1 - tau;
                float S = ((ok0 && t0 > 0.f) ? fast_exp2(INV_A * fast_log2(t0)) : 0.f)
                        + ((ok1 && t1 > 0.f) ? fast_exp2(INV_A * fast_log2(t1)) : 0.f);
                #pragma unroll
                for (int off = 32; off >= 1; off >>= 1) S += __shfl_xor(S, off, 64);
                if (S > 1.f) lo = tau; else hi = tau;
            }
            float tau = lo;
            #pragma unroll 1
            for (int it = 0; it < 2; ++it) {
                const float t0 = cv0 - tau, t1 = cv1 - tau;
                float S1 = 0.f, S2 = 0.f;
                if (ok0 && t0 > 0.f) {
                    const float l = fast_log2(t0);
                    S1 += fast_exp2(INV_A * l); S2 += fast_exp2(INV_A_M1 * l);
                }
                if (ok1 && t1 > 0.f) {
                    const float l = fast_log2(t1);
                    S1 += fast_exp2(INV_A * l); S2 += fast_exp2(INV_A_M1 * l);
                }
                #pragma unroll
                for (int off = 32; off >= 1; off >>= 1) {
                    S1 += __shfl_xor(S1, off, 64);
                    S2 += __shfl_xor(S2, off, 64);
                }
                tau += (S1 - 1.f) / (INV_A * S2);
                tau = fmaxf(fminf(tau, hi), lo);
            }

            // final p on the compact set + normalize
            const float t0 = cv0 - tau, t1 = cv1 - tau;
            float p0 = (ok0 && t0 > 0.f) ? fast_exp2(INV_A * fast_log2(t0)) : 0.f;
            float p1 = (ok1 && t1 > 0.f) ? fast_exp2(INV_A * fast_log2(t1)) : 0.f;
            float S = p0 + p1;
            #pragma unroll
            for (int off = 32; off >= 1; off >>= 1) S += __shfl_xor(S, off, 64);
            const float rnorm = 1.f / (S + 1e-12f);
            p0 *= rnorm; p1 *= rnorm;
            const int i0 = ok0 ? (int)cidx[lane] : 0;
            const int i1 = ok1 ? (int)cidx[64 + lane] : 0;
            if (ok0) cval[lane] = p0;        // cval now holds normalized p
            if (ok1) cval[64 + lane] = p1;

            // -------- attn row: zeros + scatter, vectorized writeback -------
            float* arow = Out + OUT_OFF + ((size_t)b * NSEQ + (na + r)) * NSEQ;
            #pragma unroll
            for (int seg = 0; seg < 2; ++seg) {
                #pragma unroll
                for (int z = 0; z < 4; ++z)
                    *(float4*)&prow[(z * 64 + lane) * 4] = make_float4(0.f, 0.f, 0.f, 0.f);
                if (ok0 && (i0 >> 10) == seg) prow[i0 & 1023] = p0;
                if (ok1 && (i1 >> 10) == seg) prow[i1 & 1023] = p1;
                #pragma unroll
                for (int z = 0; z < 4; ++z) {
                    const vfloat4 pv = *(const vfloat4*)&prow[(z * 64 + lane) * 4];
                    __builtin_nontemporal_store(pv,
                        (vfloat4*)&arow[seg * 1024 + (z * 64 + lane) * 4]);
                }
            }

            // -------- sparse PV: only active V rows; out dim d = lane --------
            int ii = 0;
            #pragma unroll 1
            for (; ii + 4 <= A; ii += 4) {
                const float pa = cval[ii + 0], pb = cval[ii + 1];
                const float pc = cval[ii + 2], pd = cval[ii + 3];
                const int ma = (int)cidx[ii + 0], mb = (int)cidx[ii + 1];
                const int mc = (int)cidx[ii + 2], md = (int)cidx[ii + 3];
                const float va = Vb[(size_t)ma * DHEAD + lane];
                const float vb2 = Vb[(size_t)mb * DHEAD + lane];
                const float vc = Vb[(size_t)mc * DHEAD + lane];
                const float vd = Vb[(size_t)md * DHEAD + lane];
                outacc += pa * va + pb * vb2 + pc * vc + pd * vd;
            }
            #pragma unroll 1
            for (; ii < A; ++ii)
                outacc += cval[ii] * Vb[(size_t)(int)cidx[ii] * DHEAD + lane];
        } else {
            // -------- dense fallback (rare; correctness path) ---------------
            float lo = -1.0f, hi = -1e-6f;
            #pragma unroll 1
            for (int it = 0; it < 12; ++it) {
                const float tau = 0.5f * (lo + hi);
                float S = 0.f;
                #pragma unroll
                for (int j = 0; j < 32; ++j) {
                    const float t = s[r][j] - tau;
                    const float p = fast_exp2(INV_A * fast_log2(t));
                    S += (t > 0.f) ? p : 0.f;
                }
                #pragma unroll
                for (int off = 32; off >= 1; off >>= 1) S += __shfl_xor(S, off, 64);
                if (S > 1.f) lo = tau; else hi = tau;
            }
            float tau = lo;
            #pragma unroll 1
            for (int it = 0; it < 2; ++it) {
                float S1 = 0.f, S2 = 0.f;
                #pragma unroll
                for (int j = 0; j < 32; ++j) {
                    const float t = s[r][j] - tau;
                    if (t > 0.f) {
                        const float l = fast_log2(t);
                        S1 += fast_exp2(INV_A * l); S2 += fast_exp2(INV_A_M1 * l);
                    }
                }
                #pragma unroll
                for (int off = 32; off >= 1; off >>= 1) {
                    S1 += __shfl_xor(S1, off, 64);
                    S2 += __shfl_xor(S2, off, 64);
                }
                tau += (S1 - 1.f) / (INV_A * S2);
                tau = fmaxf(fminf(tau, hi), lo);
            }
            float S = 0.f;
            #pragma unroll
            for (int j = 0; j < 32; ++j) {
                const float t = s[r][j] - tau;
                const float p = (t > 0.f) ? fast_exp2(INV_A * fast_log2(t)) : 0.f;
                s[r][j] = p;
                S += p;
            }
            #pragma unroll
            for (int off = 32; off >= 1; off >>= 1) S += __shfl_xor(S, off, 64);
            const float rnorm = 1.f / (S + 1e-12f);

            float* arow = Out + OUT_OFF + ((size_t)b * NSEQ + (na + r)) * NSEQ;
            #pragma unroll
            for (int seg = 0; seg < 2; ++seg) {
                #pragma unroll
                for (int jj = 0; jj < 16; ++jj)
                    prow[jj * 64 + lane] = s[r][seg * 16 + jj] * rnorm;
                #pragma unroll
                for (int z = 0; z < 16; ++z)
                    __builtin_nontemporal_store(prow[z * 64 + lane],
                                                &arow[seg * 1024 + z * 64 + lane]);
                #pragma unroll 4
                for (int m = 0; m < 1024; ++m)
                    outacc += prow[m] * Vb[(size_t)(seg * 1024 + m) * DHEAD + lane];
            }
        }

        Out[((size_t)b * NSEQ + (na + r)) * DHEAD + lane] = outacc;
    }
}

extern "C" void kernel_launch(void* const* d_in, const int* in_sizes, int n_in,
                              void* d_out, int out_size, void* d_ws, size_t ws_size,
                              hipStream_t stream) {
    const float* q = (const float*)d_in[0];
    const float* k = (const float*)d_in[1];
    const float* v = (const float*)d_in[2];
    float* out = (float*)d_out;
    (void)in_sizes; (void)n_in; (void)out_size; (void)d_ws; (void)ws_size;
    dim3 grid(2048), block(256);
    hipLaunchKernelGGL(entmax_attn_kernel, grid, block, 0, stream, q, k, v, out);
}